// Round 1
// baseline (540.186 us; speedup 1.0000x reference)
//
#include <hip/hip_runtime.h>

#define EMBED 1024
#define NH 16
#define HS 64
#define SEQT 2048
#define NB 4
// tokens M = NB*SEQT = 8192

typedef unsigned short u16;
typedef unsigned int u32;
typedef __attribute__((ext_vector_type(8))) __bf16 bf16x8;
typedef __attribute__((ext_vector_type(4))) float f32x4;
typedef __attribute__((ext_vector_type(4))) unsigned short u16x4;

__device__ __forceinline__ u16 f2bf(float f) {
  u32 u = __builtin_bit_cast(u32, f);
  u32 r = (u + 0x7FFFu + ((u >> 16) & 1u)) >> 16;
  return (u16)r;
}

__device__ __forceinline__ void gload_lds16(const void* g, void* l) {
  __builtin_amdgcn_global_load_lds((const __attribute__((address_space(1))) void*)g,
                                   (__attribute__((address_space(3))) void*)l, 16, 0, 0);
}

#define MFMA16(a, b, c) __builtin_amdgcn_mfma_f32_16x16x32_bf16(a, b, c, 0, 0, 0)

// ---------------- fp32 -> bf16 convert (x) ----------------
__global__ void cvt_x(const float* __restrict__ in, u16* __restrict__ out) {
  int i = (blockIdx.x * 256 + threadIdx.x) * 4;
  float4 v = *(const float4*)(in + i);
  u16x4 o;
  o[0] = f2bf(v.x); o[1] = f2bf(v.y); o[2] = f2bf(v.z); o[3] = f2bf(v.w);
  *(u16x4*)(out + i) = o;
}

// ---------------- weight transpose + convert: w[k][n] fp32 -> wt[n][k] bf16 ----------------
__global__ void wtrans(const float* __restrict__ w0, const float* __restrict__ w1,
                       const float* __restrict__ w2, const float* __restrict__ w3,
                       u16* __restrict__ t0, u16* __restrict__ t1,
                       u16* __restrict__ t2, u16* __restrict__ t3) {
  __shared__ float tile[32][33];
  const float* w; u16* t;
  switch (blockIdx.z) {
    case 0: w = w0; t = t0; break;
    case 1: w = w1; t = t1; break;
    case 2: w = w2; t = t2; break;
    default: w = w3; t = t3; break;
  }
  int n0 = blockIdx.x * 32, k0 = blockIdx.y * 32;
  int tx = threadIdx.x, ty = threadIdx.y;
#pragma unroll
  for (int r = 0; r < 4; ++r)
    tile[ty + r * 8][tx] = w[(size_t)(k0 + ty + r * 8) * EMBED + n0 + tx];
  __syncthreads();
#pragma unroll
  for (int r = 0; r < 4; ++r)
    t[(size_t)(n0 + ty + r * 8) * EMBED + k0 + tx] = f2bf(tile[tx][ty + r * 8]);
}

// ---------------- QKV projection GEMM: [8192x1024]x[1024x1024] bf16, 128x128 tile ----------------
__global__ __launch_bounds__(256, 2) void gemm_qkv(
    const u16* __restrict__ A,
    const u16* __restrict__ wqt, const u16* __restrict__ wkt, const u16* __restrict__ wvt,
    const float* __restrict__ bq, const float* __restrict__ bk, const float* __restrict__ bv,
    u16* __restrict__ qo, u16* __restrict__ ko, u16* __restrict__ vto) {
  __shared__ __align__(16) u16 As[128 * 32];
  __shared__ __align__(16) u16 Bs[128 * 32];
  int z = blockIdx.z;
  const u16* Bt = (z == 0) ? wqt : ((z == 1) ? wkt : wvt);
  const float* bias = (z == 0) ? bq : ((z == 1) ? bk : bv);
  int m0 = blockIdx.y * 128, n0 = blockIdx.x * 128;
  int tid = threadIdx.x, lane = tid & 63, wid = tid >> 6;
  int wr = wid >> 1, wc = wid & 1;
  int lr = lane & 15, lg = lane >> 4;
  int srow = lane >> 2, scol = (lane & 3) * 8;
  f32x4 zero = {0.f, 0.f, 0.f, 0.f};
  f32x4 acc[4][4];
#pragma unroll
  for (int m = 0; m < 4; ++m)
#pragma unroll
    for (int n = 0; n < 4; ++n) acc[m][n] = zero;

  for (int k0 = 0; k0 < EMBED; k0 += 32) {
    __syncthreads();
#pragma unroll
    for (int cc = 0; cc < 2; ++cc) {
      int c = wid * 2 + cc;
      gload_lds16(A + (size_t)(m0 + c * 16 + srow) * EMBED + k0 + scol, As + c * 512);
      gload_lds16(Bt + (size_t)(n0 + c * 16 + srow) * EMBED + k0 + scol, Bs + c * 512);
    }
    __syncthreads();
    bf16x8 af[4], bfr[4];
#pragma unroll
    for (int m = 0; m < 4; ++m)
      af[m] = *(const bf16x8*)(As + (wr * 64 + m * 16 + lr) * 32 + lg * 8);
#pragma unroll
    for (int n = 0; n < 4; ++n)
      bfr[n] = *(const bf16x8*)(Bs + (wc * 64 + n * 16 + lr) * 32 + lg * 8);
#pragma unroll
    for (int m = 0; m < 4; ++m)
#pragma unroll
      for (int n = 0; n < 4; ++n)
        acc[m][n] = MFMA16(af[m], bfr[n], acc[m][n]);
  }

  // epilogue: C row = m0+wr*64+m*16+lg*4+i (token), col = n0+wc*64+n*16+lr (channel)
#pragma unroll
  for (int n = 0; n < 4; ++n) {
    int col = n0 + wc * 64 + n * 16 + lr;
    float bv_ = bias[col];
    int h = col >> 6, d = col & 63;
#pragma unroll
    for (int m = 0; m < 4; ++m) {
      int r0 = m0 + wr * 64 + m * 16 + lg * 4;
      int b_ = r0 >> 11, t_ = r0 & 2047;
      if (z < 2) {
        u16* dst = (z == 0) ? qo : ko;
#pragma unroll
        for (int i = 0; i < 4; ++i)
          dst[(((size_t)(b_ * NH + h)) * SEQT + t_ + i) * HS + d] = f2bf(acc[m][n][i] + bv_);
      } else {
        u16x4 v;
#pragma unroll
        for (int i = 0; i < 4; ++i) v[i] = f2bf(acc[m][n][i] + bv_);
        *(u16x4*)(vto + (((size_t)(b_ * NH + h)) * HS + d) * SEQT + t_) = v;
      }
    }
  }
}

// ---------------- flash attention: 4 waves/block, 16 q-rows/wave, KVBLK=32 ----------------
__global__ __launch_bounds__(256, 2) void flash(
    const u16* __restrict__ q, const u16* __restrict__ k,
    const u16* __restrict__ vt, u16* __restrict__ attnb) {
  __shared__ __align__(16) u16 Ks[32 * 64];   // [key][d]
  __shared__ __align__(16) u16 Vs[64 * 32];   // [d][key]
  __shared__ __align__(16) u16 plds[4][16][32];
  int tid = threadIdx.x, lane = tid & 63, wid = tid >> 6;
  int task = blockIdx.x * 4 + wid;
  int pair = task >> 7, qblk = task & 127;
  int qrow0 = qblk * 16;
  const u16* Qh = q + ((size_t)pair * SEQT + qrow0) * HS;
  const u16* Kh = k + (size_t)pair * SEQT * HS;
  const u16* Vh = vt + (size_t)pair * HS * SEQT;
  int lr = lane & 15, lg = lane >> 4;

  bf16x8 qf0 = *(const bf16x8*)(Qh + lr * HS + lg * 8);
  bf16x8 qf1 = *(const bf16x8*)(Qh + lr * HS + 32 + lg * 8);

  f32x4 zero = {0.f, 0.f, 0.f, 0.f};
  f32x4 o[4];
#pragma unroll
  for (int n = 0; n < 4; ++n) o[n] = zero;
  float mrow[4], lrow[4];
  int qr[4];
#pragma unroll
  for (int i = 0; i < 4; ++i) { mrow[i] = -1e30f; lrow[i] = 0.f; qr[i] = qrow0 + lg * 4 + i; }

  int qblk_max = (qblk & ~3) + 3;              // block-uniform
  int niter = (qblk_max * 16 + 16 + 31) >> 5;  // KV blocks of 32

  for (int it = 0; it < niter; ++it) {
    int k0 = it * 32;
    __syncthreads();
    // stage K tile [32][64]: wave chunk = 8 rows
    gload_lds16(Kh + (size_t)(k0 + wid * 8 + (lane >> 3)) * HS + (lane & 7) * 8, Ks + wid * 512);
    // stage Vt tile [64][32]: wave chunk = 16 rows
    gload_lds16(Vh + (size_t)(wid * 16 + (lane >> 2)) * SEQT + k0 + (lane & 3) * 8, Vs + wid * 512);
    __syncthreads();

    f32x4 s[2];
#pragma unroll
    for (int nb = 0; nb < 2; ++nb) {
      bf16x8 kf0 = *(const bf16x8*)(Ks + (nb * 16 + lr) * 64 + lg * 8);
      bf16x8 kf1 = *(const bf16x8*)(Ks + (nb * 16 + lr) * 64 + 32 + lg * 8);
      f32x4 zz = zero;
      zz = MFMA16(qf0, kf0, zz);
      zz = MFMA16(qf1, kf1, zz);
      s[nb] = zz;
    }

    float rmax[4];
#pragma unroll
    for (int i = 0; i < 4; ++i) {
      float a0 = s[0][i] * 0.125f;
      if (k0 + lr > qr[i]) a0 = -3.0e38f;
      float a1 = s[1][i] * 0.125f;
      if (k0 + 16 + lr > qr[i]) a1 = -3.0e38f;
      s[0][i] = a0; s[1][i] = a1;
      rmax[i] = fmaxf(a0, a1);
    }
#pragma unroll
    for (int off = 1; off < 16; off <<= 1)
#pragma unroll
      for (int i = 0; i < 4; ++i)
        rmax[i] = fmaxf(rmax[i], __shfl_xor(rmax[i], off, 64));

    float al[4], rs[4];
#pragma unroll
    for (int i = 0; i < 4; ++i) {
      float mn = fmaxf(mrow[i], rmax[i]);
      al[i] = __expf(mrow[i] - mn);
      mrow[i] = mn;
      float p0 = __expf(s[0][i] - mn);
      float p1 = __expf(s[1][i] - mn);
      rs[i] = p0 + p1;
      plds[wid][lg * 4 + i][lr] = f2bf(p0);
      plds[wid][lg * 4 + i][16 + lr] = f2bf(p1);
    }
#pragma unroll
    for (int off = 1; off < 16; off <<= 1)
#pragma unroll
      for (int i = 0; i < 4; ++i)
        rs[i] += __shfl_xor(rs[i], off, 64);
#pragma unroll
    for (int i = 0; i < 4; ++i) lrow[i] = lrow[i] * al[i] + rs[i];
#pragma unroll
    for (int n = 0; n < 4; ++n)
#pragma unroll
      for (int i = 0; i < 4; ++i) o[n][i] *= al[i];

    // P relayout via wave-private LDS round-trip -> A-fragment
    bf16x8 pa = *(const bf16x8*)(&plds[wid][lr][lg * 8]);
#pragma unroll
    for (int n = 0; n < 4; ++n) {
      bf16x8 vf = *(const bf16x8*)(Vs + (n * 16 + lr) * 32 + lg * 8);
      o[n] = MFMA16(pa, vf, o[n]);
    }
  }

  // epilogue: attnb[b][t][h*64+d], token-major for the output GEMM
  int h = pair & 15, b_ = pair >> 4;
#pragma unroll
  for (int n = 0; n < 4; ++n) {
    int d = n * 16 + lr;
#pragma unroll
    for (int i = 0; i < 4; ++i) {
      int t_ = qrow0 + lg * 4 + i;
      attnb[((size_t)(b_ * SEQT + t_)) * EMBED + h * HS + d] = f2bf(o[n][i] / lrow[i]);
    }
  }
}

// ---------------- output projection GEMM -> fp32 out ----------------
__global__ __launch_bounds__(256, 2) void gemm_out(
    const u16* __restrict__ A, const u16* __restrict__ wot,
    const float* __restrict__ bo, float* __restrict__ out) {
  __shared__ __align__(16) u16 As[128 * 32];
  __shared__ __align__(16) u16 Bs[128 * 32];
  int m0 = blockIdx.y * 128, n0 = blockIdx.x * 128;
  int tid = threadIdx.x, lane = tid & 63, wid = tid >> 6;
  int wr = wid >> 1, wc = wid & 1;
  int lr = lane & 15, lg = lane >> 4;
  int srow = lane >> 2, scol = (lane & 3) * 8;
  f32x4 zero = {0.f, 0.f, 0.f, 0.f};
  f32x4 acc[4][4];
#pragma unroll
  for (int m = 0; m < 4; ++m)
#pragma unroll
    for (int n = 0; n < 4; ++n) acc[m][n] = zero;

  for (int k0 = 0; k0 < EMBED; k0 += 32) {
    __syncthreads();
#pragma unroll
    for (int cc = 0; cc < 2; ++cc) {
      int c = wid * 2 + cc;
      gload_lds16(A + (size_t)(m0 + c * 16 + srow) * EMBED + k0 + scol, As + c * 512);
      gload_lds16(wot + (size_t)(n0 + c * 16 + srow) * EMBED + k0 + scol, Bs + c * 512);
    }
    __syncthreads();
    bf16x8 af[4], bfr[4];
#pragma unroll
    for (int m = 0; m < 4; ++m)
      af[m] = *(const bf16x8*)(As + (wr * 64 + m * 16 + lr) * 32 + lg * 8);
#pragma unroll
    for (int n = 0; n < 4; ++n)
      bfr[n] = *(const bf16x8*)(Bs + (wc * 64 + n * 16 + lr) * 32 + lg * 8);
#pragma unroll
    for (int m = 0; m < 4; ++m)
#pragma unroll
      for (int n = 0; n < 4; ++n)
        acc[m][n] = MFMA16(af[m], bfr[n], acc[m][n]);
  }

#pragma unroll
  for (int n = 0; n < 4; ++n) {
    int col = n0 + wc * 64 + n * 16 + lr;
    float bv_ = bo[col];
#pragma unroll
    for (int m = 0; m < 4; ++m) {
      int r0 = m0 + wr * 64 + m * 16 + lg * 4;
#pragma unroll
      for (int i = 0; i < 4; ++i)
        out[(size_t)(r0 + i) * EMBED + col] = acc[m][n][i] + bv_;
    }
  }
}

extern "C" void kernel_launch(void* const* d_in, const int* in_sizes, int n_in,
                              void* d_out, int out_size, void* d_ws, size_t ws_size,
                              hipStream_t stream) {
  const float* x  = (const float*)d_in[0];
  const float* wq = (const float*)d_in[1];
  const float* bq = (const float*)d_in[2];
  const float* wk = (const float*)d_in[3];
  const float* bk = (const float*)d_in[4];
  const float* wv = (const float*)d_in[5];
  const float* bv = (const float*)d_in[6];
  const float* wo = (const float*)d_in[7];
  const float* bo = (const float*)d_in[8];
  float* out = (float*)d_out;

  char* ws = (char*)d_ws;
  const size_t XB = 16777216;      // 8192*1024*2
  const size_t WB = 2097152;       // 1024*1024*2
  const size_t QB = 16777216;      // 16*... per-tensor q/k/vt/attn bf16
  u16* xb    = (u16*)(ws);
  u16* wqbt  = (u16*)(ws + XB);
  u16* wkbt  = (u16*)(ws + XB + WB);
  u16* wvbt  = (u16*)(ws + XB + 2 * WB);
  u16* wobt  = (u16*)(ws + XB + 3 * WB);
  u16* qb    = (u16*)(ws + XB + 4 * WB);
  u16* kb    = (u16*)(ws + XB + 4 * WB + QB);
  u16* vtb   = (u16*)(ws + XB + 4 * WB + 2 * QB);
  u16* attnb = (u16*)(ws + XB + 4 * WB + 3 * QB);

  hipLaunchKernelGGL(cvt_x, dim3(8192), dim3(256), 0, stream, x, xb);
  hipLaunchKernelGGL(wtrans, dim3(32, 32, 4), dim3(32, 8), 0, stream,
                     wq, wk, wv, wo, wqbt, wkbt, wvbt, wobt);
  hipLaunchKernelGGL(gemm_qkv, dim3(8, 64, 3), dim3(256), 0, stream,
                     xb, wqbt, wkbt, wvbt, bq, bk, bv, qb, kb, vtb);
  hipLaunchKernelGGL(flash, dim3(2048), dim3(256), 0, stream, qb, kb, vtb, attnb);
  hipLaunchKernelGGL(gemm_out, dim3(8, 64), dim3(256), 0, stream, attnb, wobt, bo, out);
}

// Round 2
// 317.041 us; speedup vs baseline: 1.7038x; 1.7038x over previous
//
#include <hip/hip_runtime.h>

#define EMBED 1024
#define NH 16
#define HS 64
#define SEQT 2048
#define NB 4
// tokens M = NB*SEQT = 8192

typedef unsigned short u16;
typedef unsigned int u32;
typedef __attribute__((ext_vector_type(8))) __bf16 bf16x8;
typedef __attribute__((ext_vector_type(4))) float f32x4;
typedef __attribute__((ext_vector_type(4))) unsigned short u16x4;

__device__ __forceinline__ u16 f2bf(float f) {
  u32 u = __builtin_bit_cast(u32, f);
  u32 r = (u + 0x7FFFu + ((u >> 16) & 1u)) >> 16;
  return (u16)r;
}

__device__ __forceinline__ void gload_lds16(const void* g, void* l) {
  __builtin_amdgcn_global_load_lds((const __attribute__((address_space(1))) void*)g,
                                   (__attribute__((address_space(3))) void*)l, 16, 0, 0);
}

#define MFMA16(a, b, c) __builtin_amdgcn_mfma_f32_16x16x32_bf16(a, b, c, 0, 0, 0)

// ---------------- fp32 -> bf16 convert (x) ----------------
__global__ void cvt_x(const float* __restrict__ in, u16* __restrict__ out) {
  int i = (blockIdx.x * 256 + threadIdx.x) * 4;
  float4 v = *(const float4*)(in + i);
  u16x4 o;
  o[0] = f2bf(v.x); o[1] = f2bf(v.y); o[2] = f2bf(v.z); o[3] = f2bf(v.w);
  *(u16x4*)(out + i) = o;
}

// ---------------- weight transpose + convert: w[k][n] fp32 -> wt[n][k] bf16 ----------------
__global__ void wtrans(const float* __restrict__ w0, const float* __restrict__ w1,
                       const float* __restrict__ w2, const float* __restrict__ w3,
                       u16* __restrict__ t0, u16* __restrict__ t1,
                       u16* __restrict__ t2, u16* __restrict__ t3) {
  __shared__ float tile[32][33];
  const float* w; u16* t;
  switch (blockIdx.z) {
    case 0: w = w0; t = t0; break;
    case 1: w = w1; t = t1; break;
    case 2: w = w2; t = t2; break;
    default: w = w3; t = t3; break;
  }
  int n0 = blockIdx.x * 32, k0 = blockIdx.y * 32;
  int tx = threadIdx.x, ty = threadIdx.y;
#pragma unroll
  for (int r = 0; r < 4; ++r)
    tile[ty + r * 8][tx] = w[(size_t)(k0 + ty + r * 8) * EMBED + n0 + tx];
  __syncthreads();
#pragma unroll
  for (int r = 0; r < 4; ++r)
    t[(size_t)(n0 + ty + r * 8) * EMBED + k0 + tx] = f2bf(tile[tx][ty + r * 8]);
}

// ---------------- QKV projection GEMM: [8192x1024]x[1024x1024] bf16, 128x128 tile ----------------
__global__ __launch_bounds__(256, 2) void gemm_qkv(
    const u16* __restrict__ A,
    const u16* __restrict__ wqt, const u16* __restrict__ wkt, const u16* __restrict__ wvt,
    const float* __restrict__ bq, const float* __restrict__ bk, const float* __restrict__ bv,
    u16* __restrict__ qo, u16* __restrict__ ko, u16* __restrict__ vto) {
  __shared__ __align__(16) u16 As[128 * 32];
  __shared__ __align__(16) u16 Bs[128 * 32];
  int z = blockIdx.z;
  const u16* Bt = (z == 0) ? wqt : ((z == 1) ? wkt : wvt);
  const float* bias = (z == 0) ? bq : ((z == 1) ? bk : bv);
  // Q gets pre-scaled by hs^-0.5 * log2(e) so flash can use exp2 directly.
  const float sc = (z == 0) ? 0.18033688011112042f : 1.0f;
  int m0 = blockIdx.y * 128, n0 = blockIdx.x * 128;
  int tid = threadIdx.x, lane = tid & 63, wid = tid >> 6;
  int wr = wid >> 1, wc = wid & 1;
  int lr = lane & 15, lg = lane >> 4;
  int srow = lane >> 2, scol = (lane & 3) * 8;
  f32x4 zero = {0.f, 0.f, 0.f, 0.f};
  f32x4 acc[4][4];
#pragma unroll
  for (int m = 0; m < 4; ++m)
#pragma unroll
    for (int n = 0; n < 4; ++n) acc[m][n] = zero;

  for (int k0 = 0; k0 < EMBED; k0 += 32) {
    __syncthreads();
#pragma unroll
    for (int cc = 0; cc < 2; ++cc) {
      int c = wid * 2 + cc;
      gload_lds16(A + (size_t)(m0 + c * 16 + srow) * EMBED + k0 + scol, As + c * 512);
      gload_lds16(Bt + (size_t)(n0 + c * 16 + srow) * EMBED + k0 + scol, Bs + c * 512);
    }
    __syncthreads();
    bf16x8 af[4], bfr[4];
#pragma unroll
    for (int m = 0; m < 4; ++m)
      af[m] = *(const bf16x8*)(As + (wr * 64 + m * 16 + lr) * 32 + lg * 8);
#pragma unroll
    for (int n = 0; n < 4; ++n)
      bfr[n] = *(const bf16x8*)(Bs + (wc * 64 + n * 16 + lr) * 32 + lg * 8);
#pragma unroll
    for (int m = 0; m < 4; ++m)
#pragma unroll
      for (int n = 0; n < 4; ++n)
        acc[m][n] = MFMA16(af[m], bfr[n], acc[m][n]);
  }

  // epilogue: C row = m0+wr*64+m*16+lg*4+i (token), col = n0+wc*64+n*16+lr (channel)
#pragma unroll
  for (int n = 0; n < 4; ++n) {
    int col = n0 + wc * 64 + n * 16 + lr;
    float bv_ = bias[col];
    int h = col >> 6, d = col & 63;
#pragma unroll
    for (int m = 0; m < 4; ++m) {
      int r0 = m0 + wr * 64 + m * 16 + lg * 4;
      int b_ = r0 >> 11, t_ = r0 & 2047;
      if (z < 2) {
        u16* dst = (z == 0) ? qo : ko;
#pragma unroll
        for (int i = 0; i < 4; ++i)
          dst[(((size_t)(b_ * NH + h)) * SEQT + t_ + i) * HS + d] = f2bf((acc[m][n][i] + bv_) * sc);
      } else {
        u16x4 v;
#pragma unroll
        for (int i = 0; i < 4; ++i) v[i] = f2bf(acc[m][n][i] + bv_);
        *(u16x4*)(vto + (((size_t)(b_ * NH + h)) * HS + d) * SEQT + t_) = v;
      }
    }
  }
}

// ---------------- flash attention v2 ----------------
// 4 waves/block, QBLK=32/wave (block covers 128 q-rows), KVBLK=64.
// Paired q-tiles (g, 15-g) -> uniform 34 kv-iters/block; grid 512 = 2 blocks/CU.
// 2-phase pipeline: STAGE(t+1) issued before compute(t); one barrier per iter.
// K/V/P LDS tiles XOR-swizzled (16B chunk ^ (row&7)) via pre-swizzled gload source.
// Swapped QK^T: mfma(K,Q) -> lane owns a full kv-slice for one q-row; softmax is
// in-register + 2 shfl_xor. Q pre-scaled by hs^-0.5*log2e -> exp2f.
__global__ __launch_bounds__(256) void flash(
    const u16* __restrict__ q, const u16* __restrict__ k,
    const u16* __restrict__ vt, u16* __restrict__ attnb) {
  __shared__ __align__(16) u16 Ks[2][4096];   // [kv=64][d=64] swizzled
  __shared__ __align__(16) u16 Vs[2][4096];   // [d=64][kv=64] swizzled
  __shared__ __align__(16) u16 Pl[4][2048];   // per-wave [q=32][kv=64] swizzled
  const int tid = threadIdx.x, lane = tid & 63, wid = tid >> 6;
  const int lr = lane & 15, lg = lane >> 4;
  const int g = blockIdx.x >> 6, pair = blockIdx.x & 63;  // pair's 8 blocks share an XCD
  const u16* Qh = q + (size_t)pair * SEQT * HS;
  const u16* Kh = k + (size_t)pair * SEQT * HS;
  const u16* Vh = vt + (size_t)pair * HS * SEQT;

  // staging: wave w covers rows w*16..+15 of the 64-row tile; 2 chunks/lane.
  const int sr0 = wid * 16 + (lane >> 3);
  const int sc0 = (lane & 7) ^ (sr0 & 7);
  const int sr1 = sr0 + 8;
  const int sc1 = (lane & 7) ^ (sr1 & 7);
  const int koff0 = sr0 * 64 + sc0 * 8;
  const int koff1 = sr1 * 64 + sc1 * 8;
  const size_t voff0 = (size_t)sr0 * SEQT + sc0 * 8;
  const size_t voff1 = (size_t)sr1 * SEQT + sc1 * 8;

  auto STAGE = [&](int t, int b) {
    const u16* Kb = Kh + (size_t)t * 4096;
    const u16* Vb = Vh + (size_t)t * 64;
    gload_lds16(Kb + koff0, &Ks[b][wid * 1024]);
    gload_lds16(Kb + koff1, &Ks[b][wid * 1024 + 512]);
    gload_lds16(Vb + voff0, &Vs[b][wid * 1024]);
    gload_lds16(Vb + voff1, &Vs[b][wid * 1024 + 512]);
  };

  const int b_ = pair >> 4, h = pair & 15;

  for (int ph = 0; ph < 2; ++ph) {
    const int qtile = ph ? (15 - g) : g;
    const int qw = qtile * 128 + wid * 32;

    bf16x8 qf[2][2];
#pragma unroll
    for (int nq = 0; nq < 2; ++nq)
#pragma unroll
      for (int ks = 0; ks < 2; ++ks)
        qf[nq][ks] = *(const bf16x8*)(Qh + (size_t)(qw + nq * 16 + lr) * HS + ks * 32 + lg * 8);

    f32x4 o[2][4];
    const f32x4 zero = {0.f, 0.f, 0.f, 0.f};
#pragma unroll
    for (int mr = 0; mr < 2; ++mr)
#pragma unroll
      for (int nd = 0; nd < 4; ++nd) o[mr][nd] = zero;
    float mrow[2] = {-1e30f, -1e30f}, lrow[2] = {0.f, 0.f}, alpha[2];

    const int nt = (qtile + 1) * 2;
    int cur = 0;
    STAGE(0, 0);
    __syncthreads();

    for (int t = 0; t < nt; ++t) {
      if (t + 1 < nt) STAGE(t + 1, cur ^ 1);  // prefetch: completes under compute
      const int k0 = t * 64;

      bf16x8 kf[4][2];
#pragma unroll
      for (int mf = 0; mf < 4; ++mf) {
        const int row = mf * 16 + lr;
#pragma unroll
        for (int ks = 0; ks < 2; ++ks)
          kf[mf][ks] = *(const bf16x8*)(&Ks[cur][row * 64 + ((ks * 4 + lg) ^ (lr & 7)) * 8]);
      }
      // swapped QK^T: out col = q (lane&15), row = kv (lg*4+reg)
      f32x4 s[2][4];
#pragma unroll
      for (int nq = 0; nq < 2; ++nq)
#pragma unroll
        for (int mf = 0; mf < 4; ++mf) {
          f32x4 a = zero;
          a = MFMA16(kf[mf][0], qf[nq][0], a);
          a = MFMA16(kf[mf][1], qf[nq][1], a);
          s[nq][mf] = a;
        }
      bf16x8 vf[4][2];
#pragma unroll
      for (int nd = 0; nd < 4; ++nd) {
        const int row = nd * 16 + lr;
#pragma unroll
        for (int ks = 0; ks < 2; ++ks)
          vf[nd][ks] = *(const bf16x8*)(&Vs[cur][row * 64 + ((ks * 4 + lg) ^ (lr & 7)) * 8]);
      }

#pragma unroll
      for (int nq = 0; nq < 2; ++nq) {
        const int qmin = qw + nq * 16;
        if (k0 + 63 > qmin) {  // wave-uniform mask skip
          const int ql = qmin + lr;
#pragma unroll
          for (int mf = 0; mf < 4; ++mf) {
            const int kvb = k0 + mf * 16 + lg * 4;
#pragma unroll
            for (int r = 0; r < 4; ++r)
              if (kvb + r > ql) s[nq][mf][r] = -3.0e38f;
          }
        }
        float t0 = fmaxf(fmaxf(s[nq][0][0], s[nq][0][1]), fmaxf(s[nq][0][2], s[nq][0][3]));
        float t1 = fmaxf(fmaxf(s[nq][1][0], s[nq][1][1]), fmaxf(s[nq][1][2], s[nq][1][3]));
        float t2 = fmaxf(fmaxf(s[nq][2][0], s[nq][2][1]), fmaxf(s[nq][2][2], s[nq][2][3]));
        float t3 = fmaxf(fmaxf(s[nq][3][0], s[nq][3][1]), fmaxf(s[nq][3][2], s[nq][3][3]));
        float mx = fmaxf(fmaxf(t0, t1), fmaxf(t2, t3));
        mx = fmaxf(mx, __shfl_xor(mx, 16, 64));
        mx = fmaxf(mx, __shfl_xor(mx, 32, 64));
        const float mn = fmaxf(mrow[nq], mx);
        const float al = exp2f(mrow[nq] - mn);
        mrow[nq] = mn; alpha[nq] = al;
        float rs = 0.f;
#pragma unroll
        for (int mf = 0; mf < 4; ++mf) {
          u16x4 pk;
#pragma unroll
          for (int r = 0; r < 4; ++r) {
            const float pv = exp2f(s[nq][mf][r] - mn);
            rs += pv;
            pk[r] = f2bf(pv);
          }
          *(u16x4*)(&Pl[wid][(nq * 16 + lr) * 64 +
                             (((2 * mf + (lg >> 1)) ^ (lr & 7)) * 8 + (lg & 1) * 4)]) = pk;
        }
        rs += __shfl_xor(rs, 16, 64);
        rs += __shfl_xor(rs, 32, 64);
        lrow[nq] = lrow[nq] * al + rs;
      }

      // rescale o (o-layout rows need alpha from lr-layout lanes)
#pragma unroll
      for (int mr = 0; mr < 2; ++mr) {
        float ao[4];
#pragma unroll
        for (int r = 0; r < 4; ++r) ao[r] = __shfl(alpha[mr], lg * 4 + r, 64);
#pragma unroll
        for (int nd = 0; nd < 4; ++nd)
#pragma unroll
          for (int r = 0; r < 4; ++r) o[mr][nd][r] *= ao[r];
      }

      bf16x8 pa[2][2];
#pragma unroll
      for (int mr = 0; mr < 2; ++mr)
#pragma unroll
        for (int ks = 0; ks < 2; ++ks)
          pa[mr][ks] = *(const bf16x8*)(&Pl[wid][(mr * 16 + lr) * 64 + ((ks * 4 + lg) ^ (lr & 7)) * 8]);
#pragma unroll
      for (int mr = 0; mr < 2; ++mr)
#pragma unroll
        for (int nd = 0; nd < 4; ++nd) {
          o[mr][nd] = MFMA16(pa[mr][0], vf[nd][0], o[mr][nd]);
          o[mr][nd] = MFMA16(pa[mr][1], vf[nd][1], o[mr][nd]);
        }

      __syncthreads();  // drains prefetch vmcnt + publishes next buffer
      cur ^= 1;
    }

    // epilogue: attnb[b][t][h*64+d]
#pragma unroll
    for (int mr = 0; mr < 2; ++mr) {
      const float lv = 1.0f / lrow[mr];
      float li[4];
#pragma unroll
      for (int r = 0; r < 4; ++r) li[r] = __shfl(lv, lg * 4 + r, 64);
#pragma unroll
      for (int nd = 0; nd < 4; ++nd) {
        const int d = nd * 16 + lr;
#pragma unroll
        for (int r = 0; r < 4; ++r) {
          const int t_ = qw + mr * 16 + lg * 4 + r;
          attnb[((size_t)(b_ * SEQT + t_)) * EMBED + h * 64 + d] = f2bf(o[mr][nd][r] * li[r]);
        }
      }
    }
  }
}

// ---------------- output projection GEMM -> fp32 out ----------------
__global__ __launch_bounds__(256, 2) void gemm_out(
    const u16* __restrict__ A, const u16* __restrict__ wot,
    const float* __restrict__ bo, float* __restrict__ out) {
  __shared__ __align__(16) u16 As[128 * 32];
  __shared__ __align__(16) u16 Bs[128 * 32];
  int m0 = blockIdx.y * 128, n0 = blockIdx.x * 128;
  int tid = threadIdx.x, lane = tid & 63, wid = tid >> 6;
  int wr = wid >> 1, wc = wid & 1;
  int lr = lane & 15, lg = lane >> 4;
  int srow = lane >> 2, scol = (lane & 3) * 8;
  f32x4 zero = {0.f, 0.f, 0.f, 0.f};
  f32x4 acc[4][4];
#pragma unroll
  for (int m = 0; m < 4; ++m)
#pragma unroll
    for (int n = 0; n < 4; ++n) acc[m][n] = zero;

  for (int k0 = 0; k0 < EMBED; k0 += 32) {
    __syncthreads();
#pragma unroll
    for (int cc = 0; cc < 2; ++cc) {
      int c = wid * 2 + cc;
      gload_lds16(A + (size_t)(m0 + c * 16 + srow) * EMBED + k0 + scol, As + c * 512);
      gload_lds16(wot + (size_t)(n0 + c * 16 + srow) * EMBED + k0 + scol, Bs + c * 512);
    }
    __syncthreads();
    bf16x8 af[4], bfr[4];
#pragma unroll
    for (int m = 0; m < 4; ++m)
      af[m] = *(const bf16x8*)(As + (wr * 64 + m * 16 + lr) * 32 + lg * 8);
#pragma unroll
    for (int n = 0; n < 4; ++n)
      bfr[n] = *(const bf16x8*)(Bs + (wc * 64 + n * 16 + lr) * 32 + lg * 8);
#pragma unroll
    for (int m = 0; m < 4; ++m)
#pragma unroll
      for (int n = 0; n < 4; ++n)
        acc[m][n] = MFMA16(af[m], bfr[n], acc[m][n]);
  }

#pragma unroll
  for (int n = 0; n < 4; ++n) {
    int col = n0 + wc * 64 + n * 16 + lr;
    float bv_ = bo[col];
#pragma unroll
    for (int m = 0; m < 4; ++m) {
      int r0 = m0 + wr * 64 + m * 16 + lg * 4;
#pragma unroll
      for (int i = 0; i < 4; ++i)
        out[(size_t)(r0 + i) * EMBED + col] = acc[m][n][i] + bv_;
    }
  }
}

extern "C" void kernel_launch(void* const* d_in, const int* in_sizes, int n_in,
                              void* d_out, int out_size, void* d_ws, size_t ws_size,
                              hipStream_t stream) {
  const float* x  = (const float*)d_in[0];
  const float* wq = (const float*)d_in[1];
  const float* bq = (const float*)d_in[2];
  const float* wk = (const float*)d_in[3];
  const float* bk = (const float*)d_in[4];
  const float* wv = (const float*)d_in[5];
  const float* bv = (const float*)d_in[6];
  const float* wo = (const float*)d_in[7];
  const float* bo = (const float*)d_in[8];
  float* out = (float*)d_out;

  char* ws = (char*)d_ws;
  const size_t XB = 16777216;      // 8192*1024*2
  const size_t WB = 2097152;       // 1024*1024*2
  const size_t QB = 16777216;
  u16* xb    = (u16*)(ws);
  u16* wqbt  = (u16*)(ws + XB);
  u16* wkbt  = (u16*)(ws + XB + WB);
  u16* wvbt  = (u16*)(ws + XB + 2 * WB);
  u16* wobt  = (u16*)(ws + XB + 3 * WB);
  u16* qb    = (u16*)(ws + XB + 4 * WB);
  u16* kb    = (u16*)(ws + XB + 4 * WB + QB);
  u16* vtb   = (u16*)(ws + XB + 4 * WB + 2 * QB);
  u16* attnb = (u16*)(ws + XB + 4 * WB + 3 * QB);

  hipLaunchKernelGGL(cvt_x, dim3(8192), dim3(256), 0, stream, x, xb);
  hipLaunchKernelGGL(wtrans, dim3(32, 32, 4), dim3(32, 8), 0, stream,
                     wq, wk, wv, wo, wqbt, wkbt, wvbt, wobt);
  hipLaunchKernelGGL(gemm_qkv, dim3(8, 64, 3), dim3(256), 0, stream,
                     xb, wqbt, wkbt, wvbt, bq, bk, bv, qb, kb, vtb);
  hipLaunchKernelGGL(flash, dim3(512), dim3(256), 0, stream, qb, kb, vtb, attnb);
  hipLaunchKernelGGL(gemm_out, dim3(8, 64), dim3(256), 0, stream, attnb, wobt, bo, out);
}

// Round 3
// 295.254 us; speedup vs baseline: 1.8296x; 1.0738x over previous
//
#include <hip/hip_runtime.h>

#define EMBED 1024
#define NH 16
#define HS 64
#define SEQT 2048
#define NB 4
// tokens M = NB*SEQT = 8192

typedef unsigned short u16;
typedef unsigned int u32;
typedef __attribute__((ext_vector_type(8))) __bf16 bf16x8;
typedef __attribute__((ext_vector_type(4))) float f32x4;
typedef __attribute__((ext_vector_type(4))) unsigned short u16x4;

__device__ __forceinline__ u16 f2bf(float f) {
  __bf16 h = (__bf16)f;  // native v_cvt (RNE); pairs fuse to v_cvt_pk_bf16_f32
  return __builtin_bit_cast(u16, h);
}

__device__ __forceinline__ void gload_lds16(const void* g, void* l) {
  __builtin_amdgcn_global_load_lds((const __attribute__((address_space(1))) void*)g,
                                   (__attribute__((address_space(3))) void*)l, 16, 0, 0);
}

#define MFMA16(a, b, c) __builtin_amdgcn_mfma_f32_16x16x32_bf16(a, b, c, 0, 0, 0)

// ---------------- fp32 -> bf16 convert (x) ----------------
__global__ void cvt_x(const float* __restrict__ in, u16* __restrict__ out) {
  int i = (blockIdx.x * 256 + threadIdx.x) * 4;
  float4 v = *(const float4*)(in + i);
  u16x4 o;
  o[0] = f2bf(v.x); o[1] = f2bf(v.y); o[2] = f2bf(v.z); o[3] = f2bf(v.w);
  *(u16x4*)(out + i) = o;
}

// ---------------- weight transpose + convert: w[k][n] fp32 -> wt[n][k] bf16 ----------------
__global__ void wtrans(const float* __restrict__ w0, const float* __restrict__ w1,
                       const float* __restrict__ w2, const float* __restrict__ w3,
                       u16* __restrict__ t0, u16* __restrict__ t1,
                       u16* __restrict__ t2, u16* __restrict__ t3) {
  __shared__ float tile[32][33];
  const float* w; u16* t;
  switch (blockIdx.z) {
    case 0: w = w0; t = t0; break;
    case 1: w = w1; t = t1; break;
    case 2: w = w2; t = t2; break;
    default: w = w3; t = t3; break;
  }
  int n0 = blockIdx.x * 32, k0 = blockIdx.y * 32;
  int tx = threadIdx.x, ty = threadIdx.y;
#pragma unroll
  for (int r = 0; r < 4; ++r)
    tile[ty + r * 8][tx] = w[(size_t)(k0 + ty + r * 8) * EMBED + n0 + tx];
  __syncthreads();
#pragma unroll
  for (int r = 0; r < 4; ++r)
    t[(size_t)(n0 + ty + r * 8) * EMBED + k0 + tx] = f2bf(tile[tx][ty + r * 8]);
}

// ---------------- QKV projection GEMM: 128x128 tile, BK=32, 2-phase dbuf ----------------
__global__ __launch_bounds__(256, 2) void gemm_qkv(
    const u16* __restrict__ A,
    const u16* __restrict__ wqt, const u16* __restrict__ wkt, const u16* __restrict__ wvt,
    const float* __restrict__ bq, const float* __restrict__ bk, const float* __restrict__ bv,
    u16* __restrict__ qo, u16* __restrict__ ko, u16* __restrict__ vto) {
  __shared__ __align__(16) u16 As[2][4096];
  __shared__ __align__(16) u16 Bs[2][4096];
  int z = blockIdx.z;
  const u16* Bt = (z == 0) ? wqt : ((z == 1) ? wkt : wvt);
  const float* bias = (z == 0) ? bq : ((z == 1) ? bk : bv);
  // Q gets pre-scaled by hs^-0.5 * log2(e) so flash can use exp2 directly.
  const float sc = (z == 0) ? 0.18033688011112042f : 1.0f;
  int m0 = blockIdx.y * 128, n0 = blockIdx.x * 128;
  int tid = threadIdx.x, lane = tid & 63, wid = tid >> 6;
  int wr = wid >> 1, wc = wid & 1;
  int lr = lane & 15, lg = lane >> 4;
  int srow = lane >> 2, scol = (lane & 3) * 8;
  f32x4 zero = {0.f, 0.f, 0.f, 0.f};
  f32x4 acc[4][4];
#pragma unroll
  for (int m = 0; m < 4; ++m)
#pragma unroll
    for (int n = 0; n < 4; ++n) acc[m][n] = zero;

  auto STAGE = [&](int k0, int b) {
#pragma unroll
    for (int cc = 0; cc < 2; ++cc) {
      int c = wid * 2 + cc;
      gload_lds16(A + (size_t)(m0 + c * 16 + srow) * EMBED + k0 + scol, &As[b][c * 512]);
      gload_lds16(Bt + (size_t)(n0 + c * 16 + srow) * EMBED + k0 + scol, &Bs[b][c * 512]);
    }
  };

  STAGE(0, 0);
  __syncthreads();
  int cur = 0;
  for (int k0 = 0; k0 < EMBED; k0 += 32) {
    if (k0 + 32 < EMBED) STAGE(k0 + 32, cur ^ 1);  // prefetch under compute
    bf16x8 af[4], bfr[4];
#pragma unroll
    for (int m = 0; m < 4; ++m)
      af[m] = *(const bf16x8*)(&As[cur][(wr * 64 + m * 16 + lr) * 32 + lg * 8]);
#pragma unroll
    for (int n = 0; n < 4; ++n)
      bfr[n] = *(const bf16x8*)(&Bs[cur][(wc * 64 + n * 16 + lr) * 32 + lg * 8]);
    __builtin_amdgcn_s_setprio(1);
#pragma unroll
    for (int m = 0; m < 4; ++m)
#pragma unroll
      for (int n = 0; n < 4; ++n)
        acc[m][n] = MFMA16(af[m], bfr[n], acc[m][n]);
    __builtin_amdgcn_s_setprio(0);
    __syncthreads();  // drains prefetch vmcnt; publishes next buffer
    cur ^= 1;
  }

  // epilogue: C row = m0+wr*64+m*16+lg*4+i (token), col = n0+wc*64+n*16+lr (channel)
#pragma unroll
  for (int n = 0; n < 4; ++n) {
    int col = n0 + wc * 64 + n * 16 + lr;
    float bv_ = bias[col];
    int h = col >> 6, d = col & 63;
#pragma unroll
    for (int m = 0; m < 4; ++m) {
      int r0 = m0 + wr * 64 + m * 16 + lg * 4;
      int b_ = r0 >> 11, t_ = r0 & 2047;
      if (z < 2) {
        u16* dst = (z == 0) ? qo : ko;
#pragma unroll
        for (int i = 0; i < 4; ++i)
          dst[(((size_t)(b_ * NH + h)) * SEQT + t_ + i) * HS + d] = f2bf((acc[m][n][i] + bv_) * sc);
      } else {
        u16x4 v;
#pragma unroll
        for (int i = 0; i < 4; ++i) v[i] = f2bf(acc[m][n][i] + bv_);
        *(u16x4*)(vto + (((size_t)(b_ * NH + h)) * HS + d) * SEQT + t_) = v;
      }
    }
  }
}

// ---------------- flash attention v3 ----------------
// v2 + (a) native bf16 cvt, (b) defer-max rescale (THR=8, log2 domain), (c) setprio
// around MFMA clusters. Structure: 4 waves/block, QBLK=32/wave, KVBLK=64, paired
// q-tiles (g,15-g) for uniform load, 2-phase prefetch, XOR-swizzled K/V/P LDS,
// swapped QK^T (softmax row in-register + 2 shfl_xor).
__global__ __launch_bounds__(256) void flash(
    const u16* __restrict__ q, const u16* __restrict__ k,
    const u16* __restrict__ vt, u16* __restrict__ attnb) {
  __shared__ __align__(16) u16 Ks[2][4096];   // [kv=64][d=64] swizzled
  __shared__ __align__(16) u16 Vs[2][4096];   // [d=64][kv=64] swizzled
  __shared__ __align__(16) u16 Pl[4][2048];   // per-wave [q=32][kv=64] swizzled
  const int tid = threadIdx.x, lane = tid & 63, wid = tid >> 6;
  const int lr = lane & 15, lg = lane >> 4;
  const int g = blockIdx.x >> 6, pair = blockIdx.x & 63;  // pair's 8 blocks share an XCD
  const u16* Qh = q + (size_t)pair * SEQT * HS;
  const u16* Kh = k + (size_t)pair * SEQT * HS;
  const u16* Vh = vt + (size_t)pair * HS * SEQT;

  // staging: wave w covers rows w*16..+15 of the 64-row tile; 2 chunks/lane.
  const int sr0 = wid * 16 + (lane >> 3);
  const int sc0 = (lane & 7) ^ (sr0 & 7);
  const int sr1 = sr0 + 8;
  const int sc1 = (lane & 7) ^ (sr1 & 7);
  const int koff0 = sr0 * 64 + sc0 * 8;
  const int koff1 = sr1 * 64 + sc1 * 8;
  const size_t voff0 = (size_t)sr0 * SEQT + sc0 * 8;
  const size_t voff1 = (size_t)sr1 * SEQT + sc1 * 8;

  auto STAGE = [&](int t, int b) {
    const u16* Kb = Kh + (size_t)t * 4096;
    const u16* Vb = Vh + (size_t)t * 64;
    gload_lds16(Kb + koff0, &Ks[b][wid * 1024]);
    gload_lds16(Kb + koff1, &Ks[b][wid * 1024 + 512]);
    gload_lds16(Vb + voff0, &Vs[b][wid * 1024]);
    gload_lds16(Vb + voff1, &Vs[b][wid * 1024 + 512]);
  };

  const int b_ = pair >> 4, h = pair & 15;

  for (int ph = 0; ph < 2; ++ph) {
    const int qtile = ph ? (15 - g) : g;
    const int qw = qtile * 128 + wid * 32;

    bf16x8 qf[2][2];
#pragma unroll
    for (int nq = 0; nq < 2; ++nq)
#pragma unroll
      for (int ks = 0; ks < 2; ++ks)
        qf[nq][ks] = *(const bf16x8*)(Qh + (size_t)(qw + nq * 16 + lr) * HS + ks * 32 + lg * 8);

    f32x4 o[2][4];
    const f32x4 zero = {0.f, 0.f, 0.f, 0.f};
#pragma unroll
    for (int mr = 0; mr < 2; ++mr)
#pragma unroll
      for (int nd = 0; nd < 4; ++nd) o[mr][nd] = zero;
    float mrow[2] = {-1e30f, -1e30f}, lrow[2] = {0.f, 0.f};

    const int nt = (qtile + 1) * 2;
    int cur = 0;
    STAGE(0, 0);
    __syncthreads();

    for (int t = 0; t < nt; ++t) {
      if (t + 1 < nt) STAGE(t + 1, cur ^ 1);  // prefetch: completes under compute
      const int k0 = t * 64;

      bf16x8 kf[4][2];
#pragma unroll
      for (int mf = 0; mf < 4; ++mf) {
        const int row = mf * 16 + lr;
#pragma unroll
        for (int ks = 0; ks < 2; ++ks)
          kf[mf][ks] = *(const bf16x8*)(&Ks[cur][row * 64 + ((ks * 4 + lg) ^ (lr & 7)) * 8]);
      }
      // swapped QK^T: out col = q (lane&15), row = kv (lg*4+reg)
      f32x4 s[2][4];
      __builtin_amdgcn_s_setprio(1);
#pragma unroll
      for (int nq = 0; nq < 2; ++nq)
#pragma unroll
        for (int mf = 0; mf < 4; ++mf) {
          f32x4 a = zero;
          a = MFMA16(kf[mf][0], qf[nq][0], a);
          a = MFMA16(kf[mf][1], qf[nq][1], a);
          s[nq][mf] = a;
        }
      __builtin_amdgcn_s_setprio(0);
      bf16x8 vf[4][2];
#pragma unroll
      for (int nd = 0; nd < 4; ++nd) {
        const int row = nd * 16 + lr;
#pragma unroll
        for (int ks = 0; ks < 2; ++ks)
          vf[nd][ks] = *(const bf16x8*)(&Vs[cur][row * 64 + ((ks * 4 + lg) ^ (lr & 7)) * 8]);
      }

#pragma unroll
      for (int nq = 0; nq < 2; ++nq) {
        const int qmin = qw + nq * 16;
        if (k0 + 63 > qmin) {  // wave-uniform mask skip (diagonal tiles only)
          const int ql = qmin + lr;
#pragma unroll
          for (int mf = 0; mf < 4; ++mf) {
            const int kvb = k0 + mf * 16 + lg * 4;
#pragma unroll
            for (int r = 0; r < 4; ++r)
              if (kvb + r > ql) s[nq][mf][r] = -3.0e38f;
          }
        }
        float t0 = fmaxf(fmaxf(s[nq][0][0], s[nq][0][1]), fmaxf(s[nq][0][2], s[nq][0][3]));
        float t1 = fmaxf(fmaxf(s[nq][1][0], s[nq][1][1]), fmaxf(s[nq][1][2], s[nq][1][3]));
        float t2 = fmaxf(fmaxf(s[nq][2][0], s[nq][2][1]), fmaxf(s[nq][2][2], s[nq][2][3]));
        float t3 = fmaxf(fmaxf(s[nq][3][0], s[nq][3][1]), fmaxf(s[nq][3][2], s[nq][3][3]));
        float mx = fmaxf(fmaxf(t0, t1), fmaxf(t2, t3));
        mx = fmaxf(mx, __shfl_xor(mx, 16, 64));
        mx = fmaxf(mx, __shfl_xor(mx, 32, 64));
        // T13 defer-max: only rescale when a row's max grew past 8 (log2 domain);
        // otherwise P is bounded by 2^8, f32 accumulators tolerate it.
        if (__any(mx > mrow[nq] + 8.0f)) {
          const float mn = fmaxf(mrow[nq], mx);
          const float al = exp2f(mrow[nq] - mn);
          mrow[nq] = mn;
          lrow[nq] *= al;
          float ao[4];
#pragma unroll
          for (int r = 0; r < 4; ++r) ao[r] = __shfl(al, lg * 4 + r, 64);
#pragma unroll
          for (int nd = 0; nd < 4; ++nd)
#pragma unroll
            for (int r = 0; r < 4; ++r) o[nq][nd][r] *= ao[r];
        }
        const float mn = mrow[nq];
        float rs = 0.f;
#pragma unroll
        for (int mf = 0; mf < 4; ++mf) {
          u16x4 pk;
#pragma unroll
          for (int r = 0; r < 4; ++r) {
            const float pv = exp2f(s[nq][mf][r] - mn);
            rs += pv;
            pk[r] = f2bf(pv);
          }
          *(u16x4*)(&Pl[wid][(nq * 16 + lr) * 64 +
                             (((2 * mf + (lg >> 1)) ^ (lr & 7)) * 8 + (lg & 1) * 4)]) = pk;
        }
        rs += __shfl_xor(rs, 16, 64);
        rs += __shfl_xor(rs, 32, 64);
        lrow[nq] += rs;
      }

      bf16x8 pa[2][2];
#pragma unroll
      for (int mr = 0; mr < 2; ++mr)
#pragma unroll
        for (int ks = 0; ks < 2; ++ks)
          pa[mr][ks] = *(const bf16x8*)(&Pl[wid][(mr * 16 + lr) * 64 + ((ks * 4 + lg) ^ (lr & 7)) * 8]);
      __builtin_amdgcn_s_setprio(1);
#pragma unroll
      for (int mr = 0; mr < 2; ++mr)
#pragma unroll
        for (int nd = 0; nd < 4; ++nd) {
          o[mr][nd] = MFMA16(pa[mr][0], vf[nd][0], o[mr][nd]);
          o[mr][nd] = MFMA16(pa[mr][1], vf[nd][1], o[mr][nd]);
        }
      __builtin_amdgcn_s_setprio(0);

      __syncthreads();  // drains prefetch vmcnt + publishes next buffer
      cur ^= 1;
    }

    // epilogue: attnb[b][t][h*64+d]
#pragma unroll
    for (int mr = 0; mr < 2; ++mr) {
      const float lv = 1.0f / lrow[mr];
      float li[4];
#pragma unroll
      for (int r = 0; r < 4; ++r) li[r] = __shfl(lv, lg * 4 + r, 64);
#pragma unroll
      for (int nd = 0; nd < 4; ++nd) {
        const int d = nd * 16 + lr;
#pragma unroll
        for (int r = 0; r < 4; ++r) {
          const int t_ = qw + mr * 16 + lg * 4 + r;
          attnb[((size_t)(b_ * SEQT + t_)) * EMBED + h * 64 + d] = f2bf(o[mr][nd][r] * li[r]);
        }
      }
    }
  }
}

// ---------------- output projection GEMM -> fp32 out (2-phase dbuf) ----------------
__global__ __launch_bounds__(256, 2) void gemm_out(
    const u16* __restrict__ A, const u16* __restrict__ wot,
    const float* __restrict__ bo, float* __restrict__ out) {
  __shared__ __align__(16) u16 As[2][4096];
  __shared__ __align__(16) u16 Bs[2][4096];
  int m0 = blockIdx.y * 128, n0 = blockIdx.x * 128;
  int tid = threadIdx.x, lane = tid & 63, wid = tid >> 6;
  int wr = wid >> 1, wc = wid & 1;
  int lr = lane & 15, lg = lane >> 4;
  int srow = lane >> 2, scol = (lane & 3) * 8;
  f32x4 zero = {0.f, 0.f, 0.f, 0.f};
  f32x4 acc[4][4];
#pragma unroll
  for (int m = 0; m < 4; ++m)
#pragma unroll
    for (int n = 0; n < 4; ++n) acc[m][n] = zero;

  auto STAGE = [&](int k0, int b) {
#pragma unroll
    for (int cc = 0; cc < 2; ++cc) {
      int c = wid * 2 + cc;
      gload_lds16(A + (size_t)(m0 + c * 16 + srow) * EMBED + k0 + scol, &As[b][c * 512]);
      gload_lds16(wot + (size_t)(n0 + c * 16 + srow) * EMBED + k0 + scol, &Bs[b][c * 512]);
    }
  };

  STAGE(0, 0);
  __syncthreads();
  int cur = 0;
  for (int k0 = 0; k0 < EMBED; k0 += 32) {
    if (k0 + 32 < EMBED) STAGE(k0 + 32, cur ^ 1);
    bf16x8 af[4], bfr[4];
#pragma unroll
    for (int m = 0; m < 4; ++m)
      af[m] = *(const bf16x8*)(&As[cur][(wr * 64 + m * 16 + lr) * 32 + lg * 8]);
#pragma unroll
    for (int n = 0; n < 4; ++n)
      bfr[n] = *(const bf16x8*)(&Bs[cur][(wc * 64 + n * 16 + lr) * 32 + lg * 8]);
    __builtin_amdgcn_s_setprio(1);
#pragma unroll
    for (int m = 0; m < 4; ++m)
#pragma unroll
      for (int n = 0; n < 4; ++n)
        acc[m][n] = MFMA16(af[m], bfr[n], acc[m][n]);
    __builtin_amdgcn_s_setprio(0);
    __syncthreads();
    cur ^= 1;
  }

#pragma unroll
  for (int n = 0; n < 4; ++n) {
    int col = n0 + wc * 64 + n * 16 + lr;
    float bv_ = bo[col];
#pragma unroll
    for (int m = 0; m < 4; ++m) {
      int r0 = m0 + wr * 64 + m * 16 + lg * 4;
#pragma unroll
      for (int i = 0; i < 4; ++i)
        out[(size_t)(r0 + i) * EMBED + col] = acc[m][n][i] + bv_;
    }
  }
}

extern "C" void kernel_launch(void* const* d_in, const int* in_sizes, int n_in,
                              void* d_out, int out_size, void* d_ws, size_t ws_size,
                              hipStream_t stream) {
  const float* x  = (const float*)d_in[0];
  const float* wq = (const float*)d_in[1];
  const float* bq = (const float*)d_in[2];
  const float* wk = (const float*)d_in[3];
  const float* bk = (const float*)d_in[4];
  const float* wv = (const float*)d_in[5];
  const float* bv = (const float*)d_in[6];
  const float* wo = (const float*)d_in[7];
  const float* bo = (const float*)d_in[8];
  float* out = (float*)d_out;

  char* ws = (char*)d_ws;
  const size_t XB = 16777216;      // 8192*1024*2
  const size_t WB = 2097152;       // 1024*1024*2
  const size_t QB = 16777216;
  u16* xb    = (u16*)(ws);
  u16* wqbt  = (u16*)(ws + XB);
  u16* wkbt  = (u16*)(ws + XB + WB);
  u16* wvbt  = (u16*)(ws + XB + 2 * WB);
  u16* wobt  = (u16*)(ws + XB + 3 * WB);
  u16* qb    = (u16*)(ws + XB + 4 * WB);
  u16* kb    = (u16*)(ws + XB + 4 * WB + QB);
  u16* vtb   = (u16*)(ws + XB + 4 * WB + 2 * QB);
  u16* attnb = (u16*)(ws + XB + 4 * WB + 3 * QB);

  hipLaunchKernelGGL(cvt_x, dim3(8192), dim3(256), 0, stream, x, xb);
  hipLaunchKernelGGL(wtrans, dim3(32, 32, 4), dim3(32, 8), 0, stream,
                     wq, wk, wv, wo, wqbt, wkbt, wvbt, wobt);
  hipLaunchKernelGGL(gemm_qkv, dim3(8, 64, 3), dim3(256), 0, stream,
                     xb, wqbt, wkbt, wvbt, bq, bk, bv, qb, kb, vtb);
  hipLaunchKernelGGL(flash, dim3(512), dim3(256), 0, stream, qb, kb, vtb, attnb);
  hipLaunchKernelGGL(gemm_out, dim3(8, 64), dim3(256), 0, stream, attnb, wobt, bo, out);
}

// Round 4
// 262.901 us; speedup vs baseline: 2.0547x; 1.1231x over previous
//
#include <hip/hip_runtime.h>

#define EMBED 1024
#define NH 16
#define HS 64
#define SEQT 2048
#define NB 4
// tokens M = NB*SEQT = 8192

typedef unsigned short u16;
typedef unsigned int u32;
typedef __attribute__((ext_vector_type(8))) __bf16 bf16x8;
typedef __attribute__((ext_vector_type(4))) float f32x4;
typedef __attribute__((ext_vector_type(4))) unsigned short u16x4;

__device__ __forceinline__ u16 f2bf(float f) {
  __bf16 h = (__bf16)f;  // native v_cvt (RNE); pairs fuse to v_cvt_pk_bf16_f32
  return __builtin_bit_cast(u16, h);
}

__device__ __forceinline__ void gload_lds16(const void* g, void* l) {
  __builtin_amdgcn_global_load_lds((const __attribute__((address_space(1))) void*)g,
                                   (__attribute__((address_space(3))) void*)l, 16, 0, 0);
}

#define MFMA16(a, b, c) __builtin_amdgcn_mfma_f32_16x16x32_bf16(a, b, c, 0, 0, 0)

// ---------------- fp32 -> bf16 convert (x) ----------------
__global__ void cvt_x(const float* __restrict__ in, u16* __restrict__ out) {
  int i = (blockIdx.x * 256 + threadIdx.x) * 4;
  float4 v = *(const float4*)(in + i);
  u16x4 o;
  o[0] = f2bf(v.x); o[1] = f2bf(v.y); o[2] = f2bf(v.z); o[3] = f2bf(v.w);
  *(u16x4*)(out + i) = o;
}

// ---------------- weight transpose + convert: w[k][n] fp32 -> wt[n][k] bf16 ----------------
__global__ void wtrans(const float* __restrict__ w0, const float* __restrict__ w1,
                       const float* __restrict__ w2, const float* __restrict__ w3,
                       u16* __restrict__ t0, u16* __restrict__ t1,
                       u16* __restrict__ t2, u16* __restrict__ t3) {
  __shared__ float tile[32][33];
  const float* w; u16* t;
  switch (blockIdx.z) {
    case 0: w = w0; t = t0; break;
    case 1: w = w1; t = t1; break;
    case 2: w = w2; t = t2; break;
    default: w = w3; t = t3; break;
  }
  int n0 = blockIdx.x * 32, k0 = blockIdx.y * 32;
  int tx = threadIdx.x, ty = threadIdx.y;
#pragma unroll
  for (int r = 0; r < 4; ++r)
    tile[ty + r * 8][tx] = w[(size_t)(k0 + ty + r * 8) * EMBED + n0 + tx];
  __syncthreads();
#pragma unroll
  for (int r = 0; r < 4; ++r)
    t[(size_t)(n0 + ty + r * 8) * EMBED + k0 + tx] = f2bf(tile[tx][ty + r * 8]);
}

// ---------------- fused QKV GEMM: [8192x1024] x [1024x3072], 128x128 tile, BK=64,
// 2-phase dbuf, T2 XOR-swizzled LDS (chunk ^= row&7; source pre-swizzle = lane-only) --------
__global__ __launch_bounds__(256, 2) void gemm_qkv(
    const u16* __restrict__ A, const u16* __restrict__ Bt,   // Bt = [3072][1024] (wq|wk|wv)^T
    const float* __restrict__ bq, const float* __restrict__ bk, const float* __restrict__ bv,
    u16* __restrict__ qo, u16* __restrict__ ko, u16* __restrict__ vto) {
  __shared__ __align__(16) u16 As[2][8192];   // [128][64] swizzled
  __shared__ __align__(16) u16 Bs[2][8192];
  int m0 = blockIdx.y * 128, n0 = blockIdx.x * 128;
  int z = n0 >> 10;  // 0=q 1=k 2=v (block-uniform)
  const float* bias = (z == 0) ? bq : ((z == 1) ? bk : bv);
  const float sc = (z == 0) ? 0.18033688011112042f : 1.0f;  // hs^-0.5 * log2e folded into Q
  int tid = threadIdx.x, lane = tid & 63, wid = tid >> 6;
  int wr = wid >> 1, wc = wid & 1;
  int lr = lane & 15, lg = lane >> 4;
  const int srow_in = lane >> 3;
  const int scol_sw = ((lane & 7) ^ (lane >> 3)) * 8;  // pre-swizzled source chunk
  f32x4 zero = {0.f, 0.f, 0.f, 0.f};
  f32x4 acc[4][4];
#pragma unroll
  for (int m = 0; m < 4; ++m)
#pragma unroll
    for (int n = 0; n < 4; ++n) acc[m][n] = zero;

  auto STAGE = [&](int k0, int b) {
#pragma unroll
    for (int j = 0; j < 4; ++j) {
      int rb = (j * 4 + wid) * 8;
      gload_lds16(A + (size_t)(m0 + rb + srow_in) * EMBED + k0 + scol_sw, &As[b][rb * 64]);
      gload_lds16(Bt + (size_t)(n0 + rb + srow_in) * EMBED + k0 + scol_sw, &Bs[b][rb * 64]);
    }
  };

  STAGE(0, 0);
  __syncthreads();
  int cur = 0;
  for (int k0 = 0; k0 < EMBED; k0 += 64) {
    if (k0 + 64 < EMBED) STAGE(k0 + 64, cur ^ 1);  // prefetch under compute
    bf16x8 af[4][2], bfr[4][2];
#pragma unroll
    for (int m = 0; m < 4; ++m)
#pragma unroll
      for (int kk = 0; kk < 2; ++kk)
        af[m][kk] = *(const bf16x8*)(&As[cur][(wr * 64 + m * 16 + lr) * 64 +
                                              (((kk * 4 + lg) ^ (lr & 7)) * 8)]);
#pragma unroll
    for (int n = 0; n < 4; ++n)
#pragma unroll
      for (int kk = 0; kk < 2; ++kk)
        bfr[n][kk] = *(const bf16x8*)(&Bs[cur][(wc * 64 + n * 16 + lr) * 64 +
                                               (((kk * 4 + lg) ^ (lr & 7)) * 8)]);
    __builtin_amdgcn_s_setprio(1);
#pragma unroll
    for (int m = 0; m < 4; ++m)
#pragma unroll
      for (int n = 0; n < 4; ++n) {
        acc[m][n] = MFMA16(af[m][0], bfr[n][0], acc[m][n]);
        acc[m][n] = MFMA16(af[m][1], bfr[n][1], acc[m][n]);
      }
    __builtin_amdgcn_s_setprio(0);
    __syncthreads();  // drains prefetch vmcnt; publishes next buffer
    cur ^= 1;
  }

  // epilogue: C row = m0+wr*64+m*16+lg*4+i (token), global col = n0+wc*64+n*16+lr
#pragma unroll
  for (int n = 0; n < 4; ++n) {
    int col = n0 + wc * 64 + n * 16 + lr;
    int lcol = col & 1023;
    float bv_ = bias[lcol];
    int h = lcol >> 6, d = lcol & 63;
#pragma unroll
    for (int m = 0; m < 4; ++m) {
      int r0 = m0 + wr * 64 + m * 16 + lg * 4;
      int b_ = r0 >> 11, t_ = r0 & 2047;
      if (z < 2) {
        u16* dst = (z == 0) ? qo : ko;
#pragma unroll
        for (int i = 0; i < 4; ++i)
          dst[(((size_t)(b_ * NH + h)) * SEQT + t_ + i) * HS + d] = f2bf((acc[m][n][i] + bv_) * sc);
      } else {
        u16x4 v;
#pragma unroll
        for (int i = 0; i < 4; ++i) v[i] = f2bf(acc[m][n][i] + bv_);
        *(u16x4*)(vto + (((size_t)(b_ * NH + h)) * HS + d) * SEQT + t_) = v;
      }
    }
  }
}

// ---------------- flash attention v4 ----------------
// v3 + single q-tile per block (1024 blocks, longest-first) -> 3 blocks/CU co-resident
// (LDS 48KB, launch_bounds(256,3)): cross-block MFMA/VALU overlap. Structure otherwise:
// 4 waves/block, QBLK=32/wave, KVBLK=64, 2-phase prefetch, XOR-swizzled K/V/P LDS,
// swapped QK^T, defer-max (THR=8 log2), setprio around MFMA clusters.
__global__ __launch_bounds__(256, 3) void flash(
    const u16* __restrict__ q, const u16* __restrict__ k,
    const u16* __restrict__ vt, u16* __restrict__ attnb) {
  __shared__ __align__(16) u16 Ks[2][4096];   // [kv=64][d=64] swizzled
  __shared__ __align__(16) u16 Vs[2][4096];   // [d=64][kv=64] swizzled
  __shared__ __align__(16) u16 Pl[4][2048];   // per-wave [q=32][kv=64] swizzled
  const int tid = threadIdx.x, lane = tid & 63, wid = tid >> 6;
  const int lr = lane & 15, lg = lane >> 4;
  const int g = blockIdx.x >> 6, pair = blockIdx.x & 63;  // same-pair blocks share an XCD
  const int qtile = 15 - g;                               // longest tiles dispatch first
  const u16* Qh = q + (size_t)pair * SEQT * HS;
  const u16* Kh = k + (size_t)pair * SEQT * HS;
  const u16* Vh = vt + (size_t)pair * HS * SEQT;

  // staging: wave w covers rows w*16..+15 of the 64-row tile; 2 chunks/lane.
  const int sr0 = wid * 16 + (lane >> 3);
  const int sc0 = (lane & 7) ^ (sr0 & 7);
  const int sr1 = sr0 + 8;
  const int sc1 = (lane & 7) ^ (sr1 & 7);
  const int koff0 = sr0 * 64 + sc0 * 8;
  const int koff1 = sr1 * 64 + sc1 * 8;
  const size_t voff0 = (size_t)sr0 * SEQT + sc0 * 8;
  const size_t voff1 = (size_t)sr1 * SEQT + sc1 * 8;

  auto STAGE = [&](int t, int b) {
    const u16* Kb = Kh + (size_t)t * 4096;
    const u16* Vb = Vh + (size_t)t * 64;
    gload_lds16(Kb + koff0, &Ks[b][wid * 1024]);
    gload_lds16(Kb + koff1, &Ks[b][wid * 1024 + 512]);
    gload_lds16(Vb + voff0, &Vs[b][wid * 1024]);
    gload_lds16(Vb + voff1, &Vs[b][wid * 1024 + 512]);
  };

  const int b_ = pair >> 4, h = pair & 15;
  const int qw = qtile * 128 + wid * 32;

  bf16x8 qf[2][2];
#pragma unroll
  for (int nq = 0; nq < 2; ++nq)
#pragma unroll
    for (int ks = 0; ks < 2; ++ks)
      qf[nq][ks] = *(const bf16x8*)(Qh + (size_t)(qw + nq * 16 + lr) * HS + ks * 32 + lg * 8);

  f32x4 o[2][4];
  const f32x4 zero = {0.f, 0.f, 0.f, 0.f};
#pragma unroll
  for (int mr = 0; mr < 2; ++mr)
#pragma unroll
    for (int nd = 0; nd < 4; ++nd) o[mr][nd] = zero;
  float mrow[2] = {-1e30f, -1e30f}, lrow[2] = {0.f, 0.f};

  const int nt = (qtile + 1) * 2;
  int cur = 0;
  STAGE(0, 0);
  __syncthreads();

  for (int t = 0; t < nt; ++t) {
    if (t + 1 < nt) STAGE(t + 1, cur ^ 1);  // prefetch: completes under compute
    const int k0 = t * 64;

    bf16x8 kf[4][2];
#pragma unroll
    for (int mf = 0; mf < 4; ++mf) {
      const int row = mf * 16 + lr;
#pragma unroll
      for (int ks = 0; ks < 2; ++ks)
        kf[mf][ks] = *(const bf16x8*)(&Ks[cur][row * 64 + ((ks * 4 + lg) ^ (lr & 7)) * 8]);
    }
    // swapped QK^T: out col = q (lane&15), row = kv (lg*4+reg)
    f32x4 s[2][4];
    __builtin_amdgcn_s_setprio(1);
#pragma unroll
    for (int nq = 0; nq < 2; ++nq)
#pragma unroll
      for (int mf = 0; mf < 4; ++mf) {
        f32x4 a = zero;
        a = MFMA16(kf[mf][0], qf[nq][0], a);
        a = MFMA16(kf[mf][1], qf[nq][1], a);
        s[nq][mf] = a;
      }
    __builtin_amdgcn_s_setprio(0);
    bf16x8 vf[4][2];
#pragma unroll
    for (int nd = 0; nd < 4; ++nd) {
      const int row = nd * 16 + lr;
#pragma unroll
      for (int ks = 0; ks < 2; ++ks)
        vf[nd][ks] = *(const bf16x8*)(&Vs[cur][row * 64 + ((ks * 4 + lg) ^ (lr & 7)) * 8]);
    }

#pragma unroll
    for (int nq = 0; nq < 2; ++nq) {
      const int qmin = qw + nq * 16;
      if (k0 + 63 > qmin) {  // wave-uniform mask skip (diagonal tiles only)
        const int ql = qmin + lr;
#pragma unroll
        for (int mf = 0; mf < 4; ++mf) {
          const int kvb = k0 + mf * 16 + lg * 4;
#pragma unroll
          for (int r = 0; r < 4; ++r)
            if (kvb + r > ql) s[nq][mf][r] = -3.0e38f;
        }
      }
      float t0 = fmaxf(fmaxf(s[nq][0][0], s[nq][0][1]), fmaxf(s[nq][0][2], s[nq][0][3]));
      float t1 = fmaxf(fmaxf(s[nq][1][0], s[nq][1][1]), fmaxf(s[nq][1][2], s[nq][1][3]));
      float t2 = fmaxf(fmaxf(s[nq][2][0], s[nq][2][1]), fmaxf(s[nq][2][2], s[nq][2][3]));
      float t3 = fmaxf(fmaxf(s[nq][3][0], s[nq][3][1]), fmaxf(s[nq][3][2], s[nq][3][3]));
      float mx = fmaxf(fmaxf(t0, t1), fmaxf(t2, t3));
      mx = fmaxf(mx, __shfl_xor(mx, 16, 64));
      mx = fmaxf(mx, __shfl_xor(mx, 32, 64));
      // T13 defer-max: only rescale when a row's max grew past 8 (log2 domain)
      if (__any(mx > mrow[nq] + 8.0f)) {
        const float mn = fmaxf(mrow[nq], mx);
        const float al = exp2f(mrow[nq] - mn);
        mrow[nq] = mn;
        lrow[nq] *= al;
        float ao[4];
#pragma unroll
        for (int r = 0; r < 4; ++r) ao[r] = __shfl(al, lg * 4 + r, 64);
#pragma unroll
        for (int nd = 0; nd < 4; ++nd)
#pragma unroll
          for (int r = 0; r < 4; ++r) o[nq][nd][r] *= ao[r];
      }
      const float mn = mrow[nq];
      float rs = 0.f;
#pragma unroll
      for (int mf = 0; mf < 4; ++mf) {
        u16x4 pk;
#pragma unroll
        for (int r = 0; r < 4; ++r) {
          const float pv = exp2f(s[nq][mf][r] - mn);
          rs += pv;
          pk[r] = f2bf(pv);
        }
        *(u16x4*)(&Pl[wid][(nq * 16 + lr) * 64 +
                           (((2 * mf + (lg >> 1)) ^ (lr & 7)) * 8 + (lg & 1) * 4)]) = pk;
      }
      rs += __shfl_xor(rs, 16, 64);
      rs += __shfl_xor(rs, 32, 64);
      lrow[nq] += rs;
    }

    bf16x8 pa[2][2];
#pragma unroll
    for (int mr = 0; mr < 2; ++mr)
#pragma unroll
      for (int ks = 0; ks < 2; ++ks)
        pa[mr][ks] = *(const bf16x8*)(&Pl[wid][(mr * 16 + lr) * 64 + ((ks * 4 + lg) ^ (lr & 7)) * 8]);
    __builtin_amdgcn_s_setprio(1);
#pragma unroll
    for (int mr = 0; mr < 2; ++mr)
#pragma unroll
      for (int nd = 0; nd < 4; ++nd) {
        o[mr][nd] = MFMA16(pa[mr][0], vf[nd][0], o[mr][nd]);
        o[mr][nd] = MFMA16(pa[mr][1], vf[nd][1], o[mr][nd]);
      }
    __builtin_amdgcn_s_setprio(0);

    __syncthreads();  // drains prefetch vmcnt + publishes next buffer
    cur ^= 1;
  }

  // epilogue: attnb[b][t][h*64+d]
#pragma unroll
  for (int mr = 0; mr < 2; ++mr) {
    const float lv = 1.0f / lrow[mr];
    float li[4];
#pragma unroll
    for (int r = 0; r < 4; ++r) li[r] = __shfl(lv, lg * 4 + r, 64);
#pragma unroll
    for (int nd = 0; nd < 4; ++nd) {
      const int d = nd * 16 + lr;
#pragma unroll
      for (int r = 0; r < 4; ++r) {
        const int t_ = qw + mr * 16 + lg * 4 + r;
        attnb[((size_t)(b_ * SEQT + t_)) * EMBED + h * 64 + d] = f2bf(o[mr][nd][r] * li[r]);
      }
    }
  }
}

// ---------------- output projection GEMM -> fp32 out (BK=64, swizzled, 2-phase dbuf) ------
__global__ __launch_bounds__(256, 2) void gemm_out(
    const u16* __restrict__ A, const u16* __restrict__ wot,
    const float* __restrict__ bo, float* __restrict__ out) {
  __shared__ __align__(16) u16 As[2][8192];
  __shared__ __align__(16) u16 Bs[2][8192];
  int m0 = blockIdx.y * 128, n0 = blockIdx.x * 128;
  int tid = threadIdx.x, lane = tid & 63, wid = tid >> 6;
  int wr = wid >> 1, wc = wid & 1;
  int lr = lane & 15, lg = lane >> 4;
  const int srow_in = lane >> 3;
  const int scol_sw = ((lane & 7) ^ (lane >> 3)) * 8;
  f32x4 zero = {0.f, 0.f, 0.f, 0.f};
  f32x4 acc[4][4];
#pragma unroll
  for (int m = 0; m < 4; ++m)
#pragma unroll
    for (int n = 0; n < 4; ++n) acc[m][n] = zero;

  auto STAGE = [&](int k0, int b) {
#pragma unroll
    for (int j = 0; j < 4; ++j) {
      int rb = (j * 4 + wid) * 8;
      gload_lds16(A + (size_t)(m0 + rb + srow_in) * EMBED + k0 + scol_sw, &As[b][rb * 64]);
      gload_lds16(wot + (size_t)(n0 + rb + srow_in) * EMBED + k0 + scol_sw, &Bs[b][rb * 64]);
    }
  };

  STAGE(0, 0);
  __syncthreads();
  int cur = 0;
  for (int k0 = 0; k0 < EMBED; k0 += 64) {
    if (k0 + 64 < EMBED) STAGE(k0 + 64, cur ^ 1);
    bf16x8 af[4][2], bfr[4][2];
#pragma unroll
    for (int m = 0; m < 4; ++m)
#pragma unroll
      for (int kk = 0; kk < 2; ++kk)
        af[m][kk] = *(const bf16x8*)(&As[cur][(wr * 64 + m * 16 + lr) * 64 +
                                              (((kk * 4 + lg) ^ (lr & 7)) * 8)]);
#pragma unroll
    for (int n = 0; n < 4; ++n)
#pragma unroll
      for (int kk = 0; kk < 2; ++kk)
        bfr[n][kk] = *(const bf16x8*)(&Bs[cur][(wc * 64 + n * 16 + lr) * 64 +
                                               (((kk * 4 + lg) ^ (lr & 7)) * 8)]);
    __builtin_amdgcn_s_setprio(1);
#pragma unroll
    for (int m = 0; m < 4; ++m)
#pragma unroll
      for (int n = 0; n < 4; ++n) {
        acc[m][n] = MFMA16(af[m][0], bfr[n][0], acc[m][n]);
        acc[m][n] = MFMA16(af[m][1], bfr[n][1], acc[m][n]);
      }
    __builtin_amdgcn_s_setprio(0);
    __syncthreads();
    cur ^= 1;
  }

#pragma unroll
  for (int n = 0; n < 4; ++n) {
    int col = n0 + wc * 64 + n * 16 + lr;
    float bv_ = bo[col];
#pragma unroll
    for (int m = 0; m < 4; ++m) {
      int r0 = m0 + wr * 64 + m * 16 + lg * 4;
#pragma unroll
      for (int i = 0; i < 4; ++i)
        out[(size_t)(r0 + i) * EMBED + col] = acc[m][n][i] + bv_;
    }
  }
}

extern "C" void kernel_launch(void* const* d_in, const int* in_sizes, int n_in,
                              void* d_out, int out_size, void* d_ws, size_t ws_size,
                              hipStream_t stream) {
  const float* x  = (const float*)d_in[0];
  const float* wq = (const float*)d_in[1];
  const float* bq = (const float*)d_in[2];
  const float* wk = (const float*)d_in[3];
  const float* bk = (const float*)d_in[4];
  const float* wv = (const float*)d_in[5];
  const float* bv = (const float*)d_in[6];
  const float* wo = (const float*)d_in[7];
  const float* bo = (const float*)d_in[8];
  float* out = (float*)d_out;

  char* ws = (char*)d_ws;
  const size_t XB = 16777216;      // 8192*1024*2
  const size_t WB = 2097152;       // 1024*1024*2
  const size_t QB = 16777216;
  u16* xb     = (u16*)(ws);
  u16* wqkvbt = (u16*)(ws + XB);                    // fused [3072][1024] (wq|wk|wv)^T
  u16* wobt   = (u16*)(ws + XB + 3 * WB);
  u16* qb     = (u16*)(ws + XB + 4 * WB);
  u16* kb     = (u16*)(ws + XB + 4 * WB + QB);
  u16* vtb    = (u16*)(ws + XB + 4 * WB + 2 * QB);
  u16* attnb  = (u16*)(ws + XB + 4 * WB + 3 * QB);

  hipLaunchKernelGGL(cvt_x, dim3(8192), dim3(256), 0, stream, x, xb);
  hipLaunchKernelGGL(wtrans, dim3(32, 32, 4), dim3(32, 8), 0, stream,
                     wq, wk, wv, wo,
                     wqkvbt, wqkvbt + 1048576, wqkvbt + 2097152, wobt);
  hipLaunchKernelGGL(gemm_qkv, dim3(24, 64), dim3(256), 0, stream,
                     xb, wqkvbt, bq, bk, bv, qb, kb, vtb);
  hipLaunchKernelGGL(flash, dim3(1024), dim3(256), 0, stream, qb, kb, vtb, attnb);
  hipLaunchKernelGGL(gemm_out, dim3(8, 64), dim3(256), 0, stream, attnb, wobt, bo, out);
}